// Round 3
// baseline (87.787 us; speedup 1.0000x reference)
//
#include <hip/hip_runtime.h>
#include <hip/hip_bf16.h>

// PtrNet2: B=512, T=2048, IN=2, H=128
// Full algebraic collapse (IN=2):
//   u2[b,h,t]  = mask*(x0*P0[h] + x1*P1[h] + E[h]) + wrefB[h],  P* = Wref_W @ (enc_W@emb_W cols)
//   glimpse    = X0*P0 + X1*P1 + C*E + wrefB,  X0=sum a*m*x0, X1=sum a*m*x1, C=sum a*m
// tanh fold: sum_h vec*tanh(v_h) = Vsum - sum_h (2vec_h)*rcp(exp2(c*v_h)+1), c=2*log2(e);
// Vsum cancels in softmax => weights = exp(accmin - acc).
// Glimpse-0 query is batch-uniform => its base c*(u1+wrefB) is grid-constant (kprep).
// Score coefficients are wave-uniform => scalar loads (SGPR), not LDS: the inner loop has
// zero vector-memory ops for glimpse 0 and one broadcast ds_read_b32 per h for glimpse 1.

#define Bsz 512
#define Tsz 2048
#define Hsz 128
#define TPB 512
#define TOK 4  // Tsz / TPB

#define C2LOG2E 2.8853900817779268f
#define LOG2E   1.4426950408889634f

__device__ __forceinline__ float exp2fast(float x) { return __builtin_amdgcn_exp2f(x); }
__device__ __forceinline__ float rcpfast(float x)  { return __builtin_amdgcn_rcpf(x); }

// ---- kprep: SC={c*P0, c*P1, c*E, 2*vec}, BG0=c*(u1g0+wrefB), UC={P0,P1,E,wrefB} ----
__global__ __launch_bounds__(128) void kprep(
        const float* __restrict__ embW, const float* __restrict__ embB,
        const float* __restrict__ encW, const float* __restrict__ encB,
        const float* __restrict__ wrefW, const float* __restrict__ wrefB,
        const float* __restrict__ wqW, const float* __restrict__ wqB,
        const float* __restrict__ dec, const float* __restrict__ vec,
        float4* __restrict__ SC, float* __restrict__ BG0, float4* __restrict__ UC) {
    __shared__ float m0[Hsz], m1[Hsz], cc[Hsz], dq[Hsz];
    int h = threadIdx.x;
    float a0 = 0.f, a1 = 0.f, ac = 0.f;
    for (int k = 0; k < Hsz; ++k) {
        float w = encW[h * Hsz + k];
        a0 = fmaf(w, embW[2 * k + 0], a0);
        a1 = fmaf(w, embW[2 * k + 1], a1);
        ac = fmaf(w, embB[k], ac);
    }
    m0[h] = a0; m1[h] = a1; cc[h] = ac + encB[h]; dq[h] = dec[h];
    __syncthreads();
    float p0 = 0.f, p1 = 0.f, pe = 0.f, uq = wqB[h];
    for (int k = 0; k < Hsz; ++k) {
        float w = wrefW[h * Hsz + k];
        p0 = fmaf(w, m0[k], p0);
        p1 = fmaf(w, m1[k], p1);
        pe = fmaf(w, cc[k], pe);
        uq = fmaf(wqW[h * Hsz + k], dq[k], uq);
    }
    float wb = wrefB[h];
    SC[h]  = make_float4(C2LOG2E * p0, C2LOG2E * p1, C2LOG2E * pe, 2.f * vec[h]);
    BG0[h] = C2LOG2E * (uq + wb);
    UC[h]  = make_float4(p0, p1, pe, wb);
}

// ---- one glimpse: score (scalar-load coefficients) + softmax stats -> (X0,X1,Cm) ----
template<bool G1>
__device__ __forceinline__ void do_glimpse(
        const float2 xv[TOK], const float mk[TOK],
        const float4* __restrict__ SC, const float* __restrict__ BG0,
        const float* baseL, float* redm, float4* red4, float4* tripS,
        int tid, int wave, int lane, float& X0, float& X1, float& Cm) {
    float acc[TOK];
    #pragma unroll
    for (int j = 0; j < TOK; ++j) acc[j] = 0.f;
    #pragma unroll 4
    for (int h = 0; h < Hsz; ++h) {
        float4 cv = SC[h];                    // s_load_dwordx4 (wave-uniform)
        float bb = G1 ? baseL[h] : BG0[h];    // ds_read_b32 bcast / s_load_dword
        #pragma unroll
        for (int j = 0; j < TOK; ++j) {
            float w = fmaf(xv[j].x, cv.x, fmaf(xv[j].y, cv.y, cv.z));
            float a = fmaf(mk[j], w, bb);
            float r = rcpfast(exp2fast(a) + 1.f);
            acc[j] = fmaf(cv.w, r, acc[j]);
        }
    }
    // block min-reduce of acc (u = Vsum - acc, so min acc == max u)
    float am = fminf(fminf(acc[0], acc[1]), fminf(acc[2], acc[3]));
    for (int off = 32; off; off >>= 1) am = fminf(am, __shfl_xor(am, off));
    if (lane == 0) redm[wave] = am;
    __syncthreads();
    am = redm[0];
    #pragma unroll
    for (int w2 = 1; w2 < 8; ++w2) am = fminf(am, redm[w2]);
    // stats
    float Z = 0.f, Sm = 0.f, S0 = 0.f, S1 = 0.f;
    #pragma unroll
    for (int j = 0; j < TOK; ++j) {
        float e = exp2fast((am - acc[j]) * LOG2E);
        float em = e * mk[j];
        Z += e; Sm += em;
        S0 = fmaf(em, xv[j].x, S0);
        S1 = fmaf(em, xv[j].y, S1);
    }
    for (int off = 32; off; off >>= 1) {
        Z += __shfl_xor(Z, off); Sm += __shfl_xor(Sm, off);
        S0 += __shfl_xor(S0, off); S1 += __shfl_xor(S1, off);
    }
    if (lane == 0) red4[wave] = make_float4(Z, Sm, S0, S1);
    __syncthreads();
    if (tid == 0) {
        float Zt = 0.f, Smt = 0.f, S0t = 0.f, S1t = 0.f;
        #pragma unroll
        for (int w2 = 0; w2 < 8; ++w2) {
            Zt += red4[w2].x; Smt += red4[w2].y; S0t += red4[w2].z; S1t += red4[w2].w;
        }
        float inv = 1.f / Zt;
        *tripS = make_float4(S0t * inv, S1t * inv, Smt * inv, 0.f);
    }
    __syncthreads();
    X0 = tripS->x; X1 = tripS->y; Cm = tripS->z;
}

// ---- fused: one block per batch row, both glimpses + final head ----
__global__ __launch_bounds__(TPB) void kfused(
        const float* __restrict__ x, const float* __restrict__ mask,
        const float4* __restrict__ SC, const float* __restrict__ BG0,
        const float4* __restrict__ UC,
        const float* __restrict__ wqW, const float* __restrict__ wqB,
        const float* __restrict__ fc1, const float* __restrict__ fc2,
        float* __restrict__ out) {
    __shared__ float4 uc[Hsz];   // {P0, P1, E, wrefB}
    __shared__ float baseL[Hsz]; // glimpse-1: c*(u1+wrefB)
    __shared__ float q[Hsz], rr[Hsz];
    __shared__ float pp[4][Hsz];
    __shared__ float redm[8];
    __shared__ float4 red4[8];
    __shared__ float4 tripS;

    int b = blockIdx.x, tid = threadIdx.x;
    int wave = tid >> 6, lane = tid & 63;
    if (tid < Hsz) uc[tid] = UC[tid];

    float2 xv[TOK]; float mk[TOK];
    const float2* x2 = (const float2*)(x + (size_t)b * Tsz * 2);
    const float* mrow = mask + (size_t)b * Tsz;
    #pragma unroll
    for (int j = 0; j < TOK; ++j) { xv[j] = x2[j * TPB + tid]; mk[j] = mrow[j * TPB + tid]; }
    __syncthreads();

    float X0, X1, Cm;
    // ---- glimpse 0 (grid-uniform base, pure scalar loads) ----
    do_glimpse<false>(xv, mk, SC, BG0, baseL, redm, red4, &tripS, tid, wave, lane, X0, X1, Cm);

    // ---- glimpse-1 query + u1 matvec; baseL[h] = c*(u1+wrefB) ----
    if (tid < Hsz) {
        float4 u4 = uc[tid];
        q[tid] = fmaf(X0, u4.x, fmaf(X1, u4.y, fmaf(Cm, u4.z, u4.w)));
    }
    __syncthreads();
    {
        int h = tid & (Hsz - 1), part = tid >> 7;   // 4 parts x 32 k
        float s = 0.f;
        const float* wr = wqW + (size_t)h * Hsz + part * 32;
        #pragma unroll 8
        for (int k = 0; k < 32; ++k) s = fmaf(wr[k], q[part * 32 + k], s);
        pp[part][h] = s;
    }
    __syncthreads();
    if (tid < Hsz) {
        float u1h = wqB[tid] + ((pp[0][tid] + pp[1][tid]) + (pp[2][tid] + pp[3][tid]));
        baseL[tid] = C2LOG2E * (u1h + uc[tid].w);
    }
    __syncthreads();

    // ---- glimpse 1 (base from LDS broadcast) ----
    do_glimpse<true>(xv, mk, SC, BG0, baseL, redm, red4, &tripS, tid, wave, lane, X0, X1, Cm);

    // ---- final head: q2 -> relu(fc1 q2) -> fc2 ----
    if (tid < Hsz) {
        float4 u4 = uc[tid];
        q[tid] = fmaf(X0, u4.x, fmaf(X1, u4.y, fmaf(Cm, u4.z, u4.w)));
    }
    __syncthreads();
    {
        int h = tid & (Hsz - 1), part = tid >> 7;
        float s = 0.f;
        const float* fr = fc1 + (size_t)h * Hsz + part * 32;
        #pragma unroll 8
        for (int k = 0; k < 32; ++k) s = fmaf(fr[k], q[part * 32 + k], s);
        pp[part][h] = s;
    }
    __syncthreads();
    if (tid < Hsz) {
        rr[tid] = fmaxf(0.f, (pp[0][tid] + pp[1][tid]) + (pp[2][tid] + pp[3][tid]));
    }
    __syncthreads();
    if (tid < 128) {
        int o = tid >> 6, l = tid & 63;
        float s = fc2[o * Hsz + l] * rr[l] + fc2[o * Hsz + 64 + l] * rr[64 + l];
        for (int off = 32; off; off >>= 1) s += __shfl_xor(s, off);
        if (l == 0) out[b * 2 + o] = s;
    }
}

extern "C" void kernel_launch(void* const* d_in, const int* in_sizes, int n_in,
                              void* d_out, int out_size, void* d_ws, size_t ws_size,
                              hipStream_t stream) {
    const float* x     = (const float*)d_in[0];
    const float* mask  = (const float*)d_in[1];
    const float* embW  = (const float*)d_in[2];
    const float* embB  = (const float*)d_in[3];
    const float* encW  = (const float*)d_in[4];
    const float* encB  = (const float*)d_in[5];
    const float* dec   = (const float*)d_in[6];
    const float* vec   = (const float*)d_in[7];
    const float* wqW   = (const float*)d_in[8];
    const float* wqB   = (const float*)d_in[9];
    const float* wrefW = (const float*)d_in[10];
    const float* wrefB = (const float*)d_in[11];
    const float* fc1   = (const float*)d_in[12];
    const float* fc2   = (const float*)d_in[13];

    float* ws = (float*)d_ws;
    float4* SC = (float4*)ws;            // 128 float4
    float4* UC = (float4*)(ws + 512);    // 128 float4
    float* BG0 = ws + 1024;              // 128 floats
    float* out = (float*)d_out;

    kprep<<<1, 128, 0, stream>>>(embW, embB, encW, encB, wrefW, wrefB, wqW, wqB,
                                 dec, vec, SC, BG0, UC);
    kfused<<<Bsz, TPB, 0, stream>>>(x, mask, SC, BG0, UC, wqW, wqB, fc1, fc2, out);
}